// Round 12
// baseline (347.625 us; speedup 1.0000x reference)
//
#include <hip/hip_runtime.h>
#include <hip/hip_bf16.h>

// ---------------------------------------------------------------------------
// GCN encoder: 2x { h = x@W ; out[dst] += norm*h[src] (incl self-loop) ; +b ; relu? }
// norm = dinv[src]*dinv[dst], dinv = rsqrt(1 + indegree)
//
// h stored SLICE-MAJOR: 8 slices x [N][16 feats] bf16 (3.2 MB/slice -> one
// slice fits a 4MB XCD L2). agg blocks take slice = blockIdx & 7; blockIdx
// round-robins over XCDs, so each XCD's gathers hit its L2-resident slice.
// Fixed-capacity bucket sort (782 buckets x 2560 slots) for CSR; r9 grouping:
//  K0 wsplit+cur-init | K1 gemm1||place | K2 finalize | K3 agg1 | K4 gemm2
//  | K5 agg2.
// agg: 4 lanes/node (uint2 = 4 feats/lane), direct quad-broadcast edge loads,
// 4-deep unroll, dinv[dst] factored to epilogue, bias/ReLU fused.
// ---------------------------------------------------------------------------

#define LHSZ 800          // max buckets (N <= 102400)
#define MAXB 4096         // LDS staging slots per bucket (avg 2048)
#define CAP  2560         // fixed bucket capacity (Poisson(2048), ~11 sigma)

typedef unsigned int uint;
typedef unsigned short ushort;
typedef __attribute__((ext_vector_type(8))) short bf16x8;
typedef __attribute__((ext_vector_type(4))) float f32x4;

static __device__ __forceinline__ float bfl(uint u) { return __uint_as_float(u << 16); }
static __device__ __forceinline__ float bfh(uint u) { return __uint_as_float(u & 0xffff0000u); }
static __device__ __forceinline__ ushort f2bfu(float f) {
    __hip_bfloat16 b = __float2bfloat16(f);
    ushort u; __builtin_memcpy(&u, &b, 2); return u;
}
// truncation split: f = hi + r exactly at fp32; lo = trunc16(r) -> err ~2^-16|f|
static __device__ __forceinline__ void splitT(float f, ushort& h, ushort& l) {
    uint u = __float_as_uint(f);
    h = (ushort)(u >> 16);
    float r = f - __uint_as_float(u & 0xffff0000u);
    l = (ushort)(__float_as_uint(r) >> 16);
}

// --- K0: pre-split W1/W2 into swizzled images + init bucket cursors --------
__global__ __launch_bounds__(256) void wsplit_init(
    const float* __restrict__ W1, const float* __restrict__ W2,
    ushort* __restrict__ Ws1, ushort* __restrict__ Ws2,
    int* __restrict__ cur, int nb)
{
    int tg = blockIdx.x * 256 + threadIdx.x;      // 0..32767
    int w = tg >> 14;
    int e = tg & 16383;
    int k = e >> 7, n = e & 127;
    float f = (w ? W2 : W1)[e];
    ushort hi, lo; splitT(f, hi, lo);
    int I = (n * 128 + k) ^ ((n & 7) << 3);
    ushort* o = w ? Ws2 : Ws1;
    o[I] = hi; o[I + 16384] = lo;
    if (tg < nb) cur[tg] = tg * CAP;
}

// --- MFMA GEMM body: out = A @ W, output SLICE-MAJOR bf16 ------------------
// MODE 0: A fp32 row-major (truncation hi/lo, 3 mfma);
// MODE 1: A bf16 slice-major (2 mfma).
template <int MODE>
static __device__ __forceinline__ void gemm_body(
    ushort* Wt, const void* __restrict__ Ap, const ushort* __restrict__ Wsp,
    ushort* __restrict__ out, int M, int blk)
{
    int t = threadIdx.x;
    {   // stage pre-split W image: pure 64KB copy
        const uint4* s4 = (const uint4*)Wsp;
        uint4* d4 = (uint4*)Wt;
        #pragma unroll
        for (int j = 0; j < 16; ++j)
            d4[t + j * 256] = s4[t + j * 256];
    }
    __syncthreads();

    int wv = t >> 6, lane = t & 63;
    int g = lane >> 4;                       // k-subgroup / D row group
    int lr = lane & 15;                      // A row / B col / D col
    int rowbase = blk * 128 + wv * 32;
    int r0 = rowbase + lr, r1 = r0 + 16;
    int rc0 = min(r0, M - 1), rc1 = min(r1, M - 1);

    f32x4 acc[2][8];
    #pragma unroll
    for (int rt = 0; rt < 2; ++rt)
        #pragma unroll
        for (int ct = 0; ct < 8; ++ct)
            acc[rt][ct] = (f32x4)0.0f;

    #pragma unroll
    for (int ks = 0; ks < 4; ++ks) {
        int kof = ks * 32 + g * 8;
        bf16x8 ahi[2], alo[2];
        if (MODE == 0) {
            const float* A = (const float*)Ap;
            #pragma unroll
            for (int rt = 0; rt < 2; ++rt) {
                const float4* p = (const float4*)(A + (size_t)(rt ? rc1 : rc0) * 128 + kof);
                float4 u0 = p[0], u1 = p[1];
                float uu[8] = {u0.x, u0.y, u0.z, u0.w, u1.x, u1.y, u1.z, u1.w};
                bf16x8 ah, al;
                #pragma unroll
                for (int q = 0; q < 8; ++q) {
                    ushort hh, ll; splitT(uu[q], hh, ll);
                    ah[q] = (short)hh; al[q] = (short)ll;
                }
                ahi[rt] = ah; alo[rt] = al;
            }
        } else {
            // A slice-major: feat kof..kof+7 lives in slice kof>>4 at offset kof&15
            const ushort* A = (const ushort*)Ap;
            int sl = kof >> 4, of = kof & 15;
            ahi[0] = *(const bf16x8*)(A + ((size_t)sl * M + rc0) * 16 + of);
            ahi[1] = *(const bf16x8*)(A + ((size_t)sl * M + rc1) * 16 + of);
        }
        #pragma unroll
        for (int ct = 0; ct < 8; ++ct) {
            int n = ct * 16 + lr;
            int I = (n * 128 + kof) ^ ((n & 7) << 3);
            bf16x8 bhi = *(const bf16x8*)&Wt[I];
            bf16x8 blo = *(const bf16x8*)&Wt[I + 16384];
            #pragma unroll
            for (int rt = 0; rt < 2; ++rt) {
                acc[rt][ct] = __builtin_amdgcn_mfma_f32_16x16x32_bf16(ahi[rt], bhi, acc[rt][ct], 0, 0, 0);
                acc[rt][ct] = __builtin_amdgcn_mfma_f32_16x16x32_bf16(ahi[rt], blo, acc[rt][ct], 0, 0, 0);
                if (MODE == 0)
                    acc[rt][ct] = __builtin_amdgcn_mfma_f32_16x16x32_bf16(alo[rt], bhi, acc[rt][ct], 0, 0, 0);
            }
        }
    }

    // epilogue: D col n = ct*16+lr -> slice ct, within-slice feat lr
    #pragma unroll
    for (int rt = 0; rt < 2; ++rt) {
        #pragma unroll
        for (int r = 0; r < 4; ++r) {
            int row = rowbase + rt * 16 + g * 4 + r;
            if (row < M) {
                #pragma unroll
                for (int ct = 0; ct < 8; ++ct)
                    out[((size_t)ct * M + row) * 16 + lr] = f2bfu(acc[rt][ct][r]);
            }
        }
    }
}

template <int MODE>
__global__ __launch_bounds__(256) void gemm_mfma(
    const void* __restrict__ Ap, const ushort* __restrict__ Wsp,
    ushort* __restrict__ out, int M)
{
    __shared__ ushort Wt[2 * 128 * 128];
    gemm_body<MODE>(Wt, Ap, Wsp, out, M, blockIdx.x);
}

// --- K1: gemm1 (blocks < gemmGrid) fused with bucket_place (rest) ----------
__global__ __launch_bounds__(256) void gemm1_place(
    const float* __restrict__ x, const ushort* __restrict__ Wsp,
    ushort* __restrict__ h, int M, int gemmGrid,
    const int* __restrict__ src, const int* __restrict__ dst,
    int* __restrict__ cur, uint* __restrict__ ppack, int E, int nb, int epb)
{
    __shared__ ushort Wt[2 * 128 * 128];
    if ((int)blockIdx.x >= gemmGrid) {
        int* lhist = (int*)Wt;                    // reuse LDS
        int* gb    = lhist + LHSZ;
        int b = blockIdx.x - gemmGrid;
        int t = threadIdx.x;
        int e0 = b * epb, e1 = min(E, e0 + epb);
        for (int i = t; i < nb; i += 256) lhist[i] = 0;
        __syncthreads();
        for (int e = e0 + t; e < e1; e += 256) atomicAdd(&lhist[dst[e] >> 7], 1);
        __syncthreads();
        for (int i = t; i < nb; i += 256) {
            int v = lhist[i];
            gb[i] = v ? atomicAdd(&cur[i], v) : 0;
            lhist[i] = 0;
        }
        __syncthreads();
        for (int e = e0 + t; e < e1; e += 256) {
            int d = dst[e];
            int b2 = d >> 7;
            int r = atomicAdd(&lhist[b2], 1);
            int pos = gb[b2] + r;
            if (pos < (b2 + 1) * CAP)             // overflow guard (~11 sigma)
                ppack[pos] = (uint)src[e] | ((uint)(d & 127) << 20);
        }
        return;
    }
    gemm_body<0>(Wt, x, Wsp, h, M, blockIdx.x);
}

// --- K2: per-bucket CSR finalize -> csrsrc + meta(pos<<10|deg) + dinv ------
__global__ __launch_bounds__(256) void csr_finalize(
    const uint* __restrict__ ppack, const int* __restrict__ cur,
    int* __restrict__ csrsrc, uint* __restrict__ meta,
    float* __restrict__ dinv, int N)
{
    __shared__ int ncnt[128], sbuf[128], ncur[128];
    __shared__ int srcbuf[MAXB];
    int t = threadIdx.x;
    int b = blockIdx.x;
    int node0 = b << 7;
    int nn = min(128, N - node0);
    int base = b * CAP;
    int len = min(cur[b] - base, CAP);

    if (t < 128) ncnt[t] = 0;
    __syncthreads();
    for (int i = t; i < len; i += 256)
        atomicAdd(&ncnt[ppack[base + i] >> 20], 1);
    __syncthreads();
    if (t < 128) sbuf[t] = ncnt[t];
    __syncthreads();
    for (int d = 1; d < 128; d <<= 1) {
        int v = 0;
        if (t < 128 && t >= d) v = sbuf[t - d];
        __syncthreads();
        if (t < 128) sbuf[t] += v;
        __syncthreads();
    }
    if (t < 128) {
        int excl = sbuf[t] - ncnt[t];
        ncur[t] = excl;
        if (t < nn) {
            meta[node0 + t] = ((uint)(base + excl) << 10) | (uint)min(ncnt[t], 1023);
            dinv[node0 + t] = rsqrtf((float)(ncnt[t] + 1));
        }
    }
    __syncthreads();
    bool staged = (len <= MAXB);
    for (int i = t; i < len; i += 256) {
        uint p = ppack[base + i];
        int pos = atomicAdd(&ncur[p >> 20], 1);
        int sl = (int)(p & 0xFFFFFu);
        if (staged) srcbuf[pos] = sl;
        else        csrsrc[base + pos] = sl;
    }
    __syncthreads();
    if (staged)
        for (int i = t; i < len; i += 256) csrsrc[base + i] = srcbuf[i];
}

// --- K3/K5: slice aggregation. slice = blockIdx&7 (XCD affinity), ----------
// 4 lanes/node x uint2 (4 feats), direct quad-broadcast edge loads, 4-deep.
#define FMA4(v, wgt) do { float wf_ = (wgt); \
    acc.x += bfl((v).x) * wf_; acc.y += bfh((v).x) * wf_; \
    acc.z += bfl((v).y) * wf_; acc.w += bfh((v).y) * wf_; } while (0)

template <bool RELU, bool OUTBF>
__global__ __launch_bounds__(256) void agg_slice(
    const ushort* __restrict__ hs, const float* __restrict__ dinv,
    const uint* __restrict__ meta, const int* __restrict__ csrsrc,
    const float* __restrict__ bias, void* __restrict__ outv, int n)
{
    int t = threadIdx.x;
    int s = blockIdx.x & 7;                  // slice -> XCD via round-robin
    int node = (blockIdx.x >> 3) * 64 + (t >> 2);
    int f = t & 3;
    if (node >= n) return;

    const uint2* h2 = (const uint2*)hs + (size_t)s * n * 4;  // slice base
    float di = dinv[node];
    uint md = meta[node];
    int beg = (int)(md >> 10);
    int m = (int)(md & 1023u);

    uint2 vs = h2[(size_t)node * 4 + f];
    float4 acc = make_float4(0.0f, 0.0f, 0.0f, 0.0f);

    int j = 0;
    for (; j + 4 <= m; j += 4) {
        int s0 = csrsrc[beg + j + 0], s1 = csrsrc[beg + j + 1];
        int s2 = csrsrc[beg + j + 2], s3 = csrsrc[beg + j + 3];
        float w0 = dinv[s0], w1 = dinv[s1], w2 = dinv[s2], w3 = dinv[s3];
        uint2 v0 = h2[(size_t)(uint)s0 * 4 + f];
        uint2 v1 = h2[(size_t)(uint)s1 * 4 + f];
        uint2 v2 = h2[(size_t)(uint)s2 * 4 + f];
        uint2 v3 = h2[(size_t)(uint)s3 * 4 + f];
        FMA4(v0, w0); FMA4(v1, w1); FMA4(v2, w2); FMA4(v3, w3);
    }
    for (; j < m; ++j) {
        int s0 = csrsrc[beg + j];
        float w0 = dinv[s0];
        uint2 v0 = h2[(size_t)(uint)s0 * 4 + f];
        FMA4(v0, w0);
    }

    // acc = edge_sum * di + self * di^2 + bias
    float sw = di * di;
    acc.x = acc.x * di + bfl(vs.x) * sw;
    acc.y = acc.y * di + bfh(vs.x) * sw;
    acc.z = acc.z * di + bfl(vs.y) * sw;
    acc.w = acc.w * di + bfh(vs.y) * sw;
    float4 bb = ((const float4*)bias)[s * 4 + f];
    acc.x += bb.x; acc.y += bb.y; acc.z += bb.z; acc.w += bb.w;
    if (RELU) {
        acc.x = fmaxf(acc.x, 0.0f); acc.y = fmaxf(acc.y, 0.0f);
        acc.z = fmaxf(acc.z, 0.0f); acc.w = fmaxf(acc.w, 0.0f);
    }
    if (OUTBF) {
        uint2 o;
        o.x = (uint)f2bfu(acc.x) | ((uint)f2bfu(acc.y) << 16);
        o.y = (uint)f2bfu(acc.z) | ((uint)f2bfu(acc.w) << 16);
        ((uint2*)outv)[((size_t)s * n + node) * 4 + f] = o;   // slice-major bf16
    } else {
        ((float4*)outv)[(size_t)node * 32 + s * 4 + f] = acc; // row-major fp32
    }
}

extern "C" void kernel_launch(void* const* d_in, const int* in_sizes, int n_in,
                              void* d_out, int out_size, void* d_ws, size_t ws_size,
                              hipStream_t stream)
{
    const float* x  = (const float*)d_in[0];
    const int*   ei = (const int*)d_in[1];
    const float* W1 = (const float*)d_in[2];
    const float* b1 = (const float*)d_in[3];
    const float* W2 = (const float*)d_in[4];
    const float* b2 = (const float*)d_in[5];

    const int N = in_sizes[0] / 128;
    const int E = in_sizes[1] / 2;
    const int* esrc = ei;         // edge_index[0]
    const int* edst = ei + E;     // edge_index[1]
    const int nb = (N + 127) >> 7;           // 782 buckets

    char* ws = (char*)d_ws;
    size_t off = 0;
    auto alloc = [&](size_t bytes) -> void* {
        void* p = ws + off;
        off += (bytes + 255) & ~(size_t)255;
        return p;
    };
    ushort* h      = (ushort*)alloc((size_t)N * 128 * sizeof(ushort));   // bf16 h (slice-major)
    uint*   ppack  = (uint*)  alloc((size_t)nb * CAP * sizeof(uint));
    int*    csrsrc = (int*)   alloc((size_t)nb * CAP * sizeof(int));
    uint*   meta   = (uint*)  alloc((size_t)N * sizeof(uint));
    float*  dinv   = (float*) alloc((size_t)N * sizeof(float));
    int*    cur    = (int*)   alloc((size_t)nb * sizeof(int));
    ushort* Ws1    = (ushort*)alloc(2 * 128 * 128 * sizeof(ushort));
    ushort* Ws2    = (ushort*)alloc(2 * 128 * 128 * sizeof(ushort));

    const int gridP = 512;
    const int epb = (E + gridP - 1) / gridP;
    const int gemmGrid = (N + 127) / 128;
    const int aggGrid = 8 * ((N + 63) / 64);

    // K0: W pre-split + cursor init
    wsplit_init<<<128, 256, 0, stream>>>(W1, W2, Ws1, Ws2, cur, nb);
    // K1: gemm1 (x@W1 -> h slice-major bf16) || bucket_place
    gemm1_place<<<gemmGrid + gridP, 256, 0, stream>>>(x, Ws1, h, N, gemmGrid,
                                                      esrc, edst, cur, ppack,
                                                      E, nb, epb);
    // K2: finalize -> csrsrc + meta + dinv
    csr_finalize<<<nb, 256, 0, stream>>>(ppack, cur, csrsrc, meta, dinv, N);
    // K3: layer-1 aggregate -> d_out (slice-major bf16 scratch)
    agg_slice<true, true><<<aggGrid, 256, 0, stream>>>(h, dinv, meta, csrsrc,
                                                       b1, d_out, N);
    // K4: gemm2 (d_out@W2 -> h slice-major bf16)
    gemm_mfma<1><<<gemmGrid, 256, 0, stream>>>(d_out, Ws2, h, N);
    // K5: layer-2 aggregate -> d_out (row-major fp32 final)
    agg_slice<false, false><<<aggGrid, 256, 0, stream>>>(h, dinv, meta, csrsrc,
                                                         b2, d_out, N);
}

// Round 13
// 194.979 us; speedup vs baseline: 1.7829x; 1.7829x over previous
//
#include <hip/hip_runtime.h>
#include <hip/hip_bf16.h>

// ---------------------------------------------------------------------------
// GCN encoder: 2x { h = x@W ; out[dst] += norm*h[src] (incl self-loop) ; +b ; relu? }
// norm = dinv[src]*dinv[dst], dinv = rsqrt(1 + indegree)
//
// CSR build via FIXED-CAPACITY bucket sort (782 buckets of 128 dst nodes,
// 2560 slots each; Poisson(2048) totals make overflow ~11-sigma). No scan,
// no count pass: cursors start at b*CAP, bucket_place runs CONCURRENTLY with
// gemm1 in one fused dispatch. csr_finalize emits meta[node]=pos<<10|deg.
// GEMM via MFMA bf16 split-precision; W pre-split once into swizzled images.
// Aggregate (best measured, r4/r8/r9): 2 nodes/wave x uint2 gathers,
// LDS-staged 32-edge batches, nq-bounded 4-deep unroll, 256-thr blocks.
// Pipeline: K0{wsplit+curinit} K1{gemm1||place} K2{finalize} K3{agg1}
//           K4{gemm2} K5{agg2}   (6 dispatches) — round-9 best, 195 us.
// ---------------------------------------------------------------------------

#define LHSZ 800          // max buckets (N <= 102400)
#define MAXB 4096         // LDS staging slots per bucket (avg 2048)
#define CAP  2560         // fixed bucket capacity

typedef unsigned int uint;
typedef unsigned short ushort;
typedef __attribute__((ext_vector_type(8))) short bf16x8;
typedef __attribute__((ext_vector_type(4))) float f32x4;

static __device__ __forceinline__ float bfl(uint u) { return __uint_as_float(u << 16); }
static __device__ __forceinline__ float bfh(uint u) { return __uint_as_float(u & 0xffff0000u); }
static __device__ __forceinline__ ushort f2bfu(float f) {
    __hip_bfloat16 b = __float2bfloat16(f);
    ushort u; __builtin_memcpy(&u, &b, 2); return u;
}
// truncation split: f = hi + r exactly at fp32; lo = trunc16(r) -> err ~2^-16|f|
static __device__ __forceinline__ void splitT(float f, ushort& h, ushort& l) {
    uint u = __float_as_uint(f);
    h = (ushort)(u >> 16);
    float r = f - __uint_as_float(u & 0xffff0000u);
    l = (ushort)(__float_as_uint(r) >> 16);
}

// --- K0: pre-split W1/W2 into swizzled images + init bucket cursors --------
__global__ __launch_bounds__(256) void wsplit_init(
    const float* __restrict__ W1, const float* __restrict__ W2,
    ushort* __restrict__ Ws1, ushort* __restrict__ Ws2,
    int* __restrict__ cur, int nb)
{
    int tg = blockIdx.x * 256 + threadIdx.x;      // 0..32767
    int w = tg >> 14;
    int e = tg & 16383;
    int k = e >> 7, n = e & 127;
    float f = (w ? W2 : W1)[e];
    ushort hi, lo; splitT(f, hi, lo);
    int I = (n * 128 + k) ^ ((n & 7) << 3);
    ushort* o = w ? Ws2 : Ws1;
    o[I] = hi; o[I + 16384] = lo;
    if (tg < nb) cur[tg] = tg * CAP;
}

// --- MFMA GEMM body: out_bf16[M x 128] = A @ W (Wsp = pre-split LDS image) -
// MODE 0: A fp32 (truncation hi/lo, 3 mfma); MODE 1: A bf16 (2 mfma).
template <int MODE>
static __device__ __forceinline__ void gemm_body(
    ushort* Wt, const void* __restrict__ Ap, const ushort* __restrict__ Wsp,
    ushort* __restrict__ out, int M, int blk)
{
    int t = threadIdx.x;
    {   // stage pre-split W image: pure 64KB copy
        const uint4* s4 = (const uint4*)Wsp;
        uint4* d4 = (uint4*)Wt;
        #pragma unroll
        for (int j = 0; j < 16; ++j)
            d4[t + j * 256] = s4[t + j * 256];
    }
    __syncthreads();

    int wv = t >> 6, lane = t & 63;
    int g = lane >> 4;                       // k-subgroup / D row group
    int lr = lane & 15;                      // A row / B col / D col
    int rowbase = blk * 128 + wv * 32;
    int r0 = rowbase + lr, r1 = r0 + 16;
    int rc0 = min(r0, M - 1), rc1 = min(r1, M - 1);

    f32x4 acc[2][8];
    #pragma unroll
    for (int rt = 0; rt < 2; ++rt)
        #pragma unroll
        for (int ct = 0; ct < 8; ++ct)
            acc[rt][ct] = (f32x4)0.0f;

    #pragma unroll
    for (int ks = 0; ks < 4; ++ks) {
        int kof = ks * 32 + g * 8;
        bf16x8 ahi[2], alo[2];
        if (MODE == 0) {
            const float* A = (const float*)Ap;
            #pragma unroll
            for (int rt = 0; rt < 2; ++rt) {
                const float4* p = (const float4*)(A + (size_t)(rt ? rc1 : rc0) * 128 + kof);
                float4 u0 = p[0], u1 = p[1];
                float uu[8] = {u0.x, u0.y, u0.z, u0.w, u1.x, u1.y, u1.z, u1.w};
                bf16x8 ah, al;
                #pragma unroll
                for (int q = 0; q < 8; ++q) {
                    ushort hh, ll; splitT(uu[q], hh, ll);
                    ah[q] = (short)hh; al[q] = (short)ll;
                }
                ahi[rt] = ah; alo[rt] = al;
            }
        } else {
            const ushort* A = (const ushort*)Ap;
            ahi[0] = *(const bf16x8*)(A + (size_t)rc0 * 128 + kof);
            ahi[1] = *(const bf16x8*)(A + (size_t)rc1 * 128 + kof);
        }
        #pragma unroll
        for (int ct = 0; ct < 8; ++ct) {
            int n = ct * 16 + lr;
            int I = (n * 128 + kof) ^ ((n & 7) << 3);
            bf16x8 bhi = *(const bf16x8*)&Wt[I];
            bf16x8 blo = *(const bf16x8*)&Wt[I + 16384];
            #pragma unroll
            for (int rt = 0; rt < 2; ++rt) {
                acc[rt][ct] = __builtin_amdgcn_mfma_f32_16x16x32_bf16(ahi[rt], bhi, acc[rt][ct], 0, 0, 0);
                acc[rt][ct] = __builtin_amdgcn_mfma_f32_16x16x32_bf16(ahi[rt], blo, acc[rt][ct], 0, 0, 0);
                if (MODE == 0)
                    acc[rt][ct] = __builtin_amdgcn_mfma_f32_16x16x32_bf16(alo[rt], bhi, acc[rt][ct], 0, 0, 0);
            }
        }
    }

    #pragma unroll
    for (int rt = 0; rt < 2; ++rt) {
        #pragma unroll
        for (int r = 0; r < 4; ++r) {
            int row = rowbase + rt * 16 + g * 4 + r;
            if (row < M) {
                #pragma unroll
                for (int ct = 0; ct < 8; ++ct)
                    out[(size_t)row * 128 + ct * 16 + lr] = f2bfu(acc[rt][ct][r]);
            }
        }
    }
}

template <int MODE>
__global__ __launch_bounds__(256) void gemm_mfma(
    const void* __restrict__ Ap, const ushort* __restrict__ Wsp,
    ushort* __restrict__ out, int M)
{
    __shared__ ushort Wt[2 * 128 * 128];
    gemm_body<MODE>(Wt, Ap, Wsp, out, M, blockIdx.x);
}

// --- K1: gemm1 (blocks < gemmGrid) fused with bucket_place (rest) ----------
// place: per-block LDS hist -> one atomicAdd(cur[b], v) reservation -> LDS
// rank -> burst writes of packed (src | dlocal<<20) into bucket region.
__global__ __launch_bounds__(256) void gemm1_place(
    const float* __restrict__ x, const ushort* __restrict__ Wsp,
    ushort* __restrict__ h, int M, int gemmGrid,
    const int* __restrict__ src, const int* __restrict__ dst,
    int* __restrict__ cur, uint* __restrict__ ppack, int E, int nb, int epb)
{
    __shared__ ushort Wt[2 * 128 * 128];
    if ((int)blockIdx.x >= gemmGrid) {
        int* lhist = (int*)Wt;                    // reuse LDS
        int* gb    = lhist + LHSZ;
        int b = blockIdx.x - gemmGrid;
        int t = threadIdx.x;
        int e0 = b * epb, e1 = min(E, e0 + epb);
        for (int i = t; i < nb; i += 256) lhist[i] = 0;
        __syncthreads();
        for (int e = e0 + t; e < e1; e += 256) atomicAdd(&lhist[dst[e] >> 7], 1);
        __syncthreads();
        for (int i = t; i < nb; i += 256) {
            int v = lhist[i];
            gb[i] = v ? atomicAdd(&cur[i], v) : 0;
            lhist[i] = 0;
        }
        __syncthreads();
        for (int e = e0 + t; e < e1; e += 256) {
            int d = dst[e];
            int b2 = d >> 7;
            int r = atomicAdd(&lhist[b2], 1);
            int pos = gb[b2] + r;
            if (pos < (b2 + 1) * CAP)             // overflow guard (~11 sigma)
                ppack[pos] = (uint)src[e] | ((uint)(d & 127) << 20);
        }
        return;
    }
    gemm_body<0>(Wt, x, Wsp, h, M, blockIdx.x);
}

// --- K2: per-bucket CSR finalize -> csrsrc + meta(pos<<10|deg) + dinv ------
__global__ __launch_bounds__(256) void csr_finalize(
    const uint* __restrict__ ppack, const int* __restrict__ cur,
    int* __restrict__ csrsrc, uint* __restrict__ meta,
    float* __restrict__ dinv, int N)
{
    __shared__ int ncnt[128], sbuf[128], ncur[128];
    __shared__ int srcbuf[MAXB];
    int t = threadIdx.x;
    int b = blockIdx.x;
    int node0 = b << 7;
    int nn = min(128, N - node0);
    int base = b * CAP;
    int len = min(cur[b] - base, CAP);

    if (t < 128) ncnt[t] = 0;
    __syncthreads();
    for (int i = t; i < len; i += 256)
        atomicAdd(&ncnt[ppack[base + i] >> 20], 1);
    __syncthreads();
    if (t < 128) sbuf[t] = ncnt[t];
    __syncthreads();
    for (int d = 1; d < 128; d <<= 1) {
        int v = 0;
        if (t < 128 && t >= d) v = sbuf[t - d];
        __syncthreads();
        if (t < 128) sbuf[t] += v;
        __syncthreads();
    }
    if (t < 128) {
        int excl = sbuf[t] - ncnt[t];
        ncur[t] = excl;
        if (t < nn) {
            meta[node0 + t] = ((uint)(base + excl) << 10) | (uint)min(ncnt[t], 1023);
            dinv[node0 + t] = rsqrtf((float)(ncnt[t] + 1));
        }
    }
    __syncthreads();
    bool staged = (len <= MAXB);
    for (int i = t; i < len; i += 256) {
        uint p = ppack[base + i];
        int pos = atomicAdd(&ncur[p >> 20], 1);
        int sl = (int)(p & 0xFFFFFu);
        if (staged) srcbuf[pos] = sl;
        else        csrsrc[base + pos] = sl;
    }
    __syncthreads();
    if (staged)
        for (int i = t; i < len; i += 256) csrsrc[base + i] = srcbuf[i];
}

// --- K3/K5: aggregation (r4 best): 2 nodes/wave, uint2 gathers, 4-deep -----
#define FMA4(v, wgt) do { float wf_ = (wgt); \
    acc.x += bfl((v).x) * wf_; acc.y += bfh((v).x) * wf_; \
    acc.z += bfl((v).y) * wf_; acc.w += bfh((v).y) * wf_; } while (0)

template <bool RELU, bool OUTBF>
__global__ __launch_bounds__(256) void agg_kernel(
    const ushort* __restrict__ h, const float* __restrict__ dinv,
    const uint* __restrict__ meta, const int* __restrict__ csrsrc,
    const float* __restrict__ bias, void* __restrict__ outv, int n)
{
    __shared__ int2 epair[4][64];
    int wv = threadIdx.x >> 6;
    int lane = threadIdx.x & 63;
    int half = lane >> 5, sub = lane & 31;
    int node = (blockIdx.x * 4 + wv) * 2 + half;
    bool active = node < n;
    int nodeC = active ? node : (n - 1);

    const uint2* h2 = (const uint2*)h;
    float di = dinv[nodeC];
    uint md = meta[nodeC];
    int beg = (int)(md >> 10);
    int m = (int)(md & 1023u);

    uint2 vs = h2[(size_t)nodeC * 32 + sub];
    float w0 = di * di;
    float4 acc;
    acc.x = bfl(vs.x) * w0; acc.y = bfh(vs.x) * w0;
    acc.z = bfl(vs.y) * w0; acc.w = bfh(vs.y) * w0;

    int mA = __shfl(m, 0), mB = __shfl(m, 32);
    int mmax = max(mA, mB);

    for (int eb = 0; eb < mmax; eb += 32) {
        int sl = 0; float dlw = 0.0f;
        if (active && (eb + sub) < m) {
            sl = csrsrc[beg + eb + sub];
            dlw = di * dinv[sl];
        }
        epair[wv][lane] = make_int2(sl, __float_as_int(dlw));
        int nq = mmax - eb; if (nq > 32) nq = 32;
        const int2* ep = &epair[wv][half * 32];
        for (int j = 0; j < nq; j += 4) {
            int2 p0 = ep[j + 0];
            int2 p1 = ep[j + 1];
            int2 p2 = ep[j + 2];
            int2 p3 = ep[j + 3];
            uint2 v0 = h2[(size_t)(uint)p0.x * 32 + sub];
            uint2 v1 = h2[(size_t)(uint)p1.x * 32 + sub];
            uint2 v2 = h2[(size_t)(uint)p2.x * 32 + sub];
            uint2 v3 = h2[(size_t)(uint)p3.x * 32 + sub];
            FMA4(v0, __int_as_float(p0.y));
            FMA4(v1, __int_as_float(p1.y));
            FMA4(v2, __int_as_float(p2.y));
            FMA4(v3, __int_as_float(p3.y));
        }
    }

    float4 bb = ((const float4*)bias)[sub];
    acc.x += bb.x; acc.y += bb.y; acc.z += bb.z; acc.w += bb.w;
    if (RELU) {
        acc.x = fmaxf(acc.x, 0.0f); acc.y = fmaxf(acc.y, 0.0f);
        acc.z = fmaxf(acc.z, 0.0f); acc.w = fmaxf(acc.w, 0.0f);
    }
    if (active) {
        if (OUTBF) {
            uint2 o;
            o.x = (uint)f2bfu(acc.x) | ((uint)f2bfu(acc.y) << 16);
            o.y = (uint)f2bfu(acc.z) | ((uint)f2bfu(acc.w) << 16);
            ((uint2*)outv)[(size_t)node * 32 + sub] = o;
        } else {
            ((float4*)outv)[(size_t)node * 32 + sub] = acc;
        }
    }
}

extern "C" void kernel_launch(void* const* d_in, const int* in_sizes, int n_in,
                              void* d_out, int out_size, void* d_ws, size_t ws_size,
                              hipStream_t stream)
{
    const float* x  = (const float*)d_in[0];
    const int*   ei = (const int*)d_in[1];
    const float* W1 = (const float*)d_in[2];
    const float* b1 = (const float*)d_in[3];
    const float* W2 = (const float*)d_in[4];
    const float* b2 = (const float*)d_in[5];

    const int N = in_sizes[0] / 128;
    const int E = in_sizes[1] / 2;
    const int* esrc = ei;         // edge_index[0]
    const int* edst = ei + E;     // edge_index[1]
    const int nb = (N + 127) >> 7;           // 782 buckets

    char* ws = (char*)d_ws;
    size_t off = 0;
    auto alloc = [&](size_t bytes) -> void* {
        void* p = ws + off;
        off += (bytes + 255) & ~(size_t)255;
        return p;
    };
    ushort* h      = (ushort*)alloc((size_t)N * 128 * sizeof(ushort));   // bf16 h
    uint*   ppack  = (uint*)  alloc((size_t)nb * CAP * sizeof(uint));
    int*    csrsrc = (int*)   alloc((size_t)nb * CAP * sizeof(int));
    uint*   meta   = (uint*)  alloc((size_t)N * sizeof(uint));
    float*  dinv   = (float*) alloc((size_t)N * sizeof(float));
    int*    cur    = (int*)   alloc((size_t)nb * sizeof(int));
    ushort* Ws1    = (ushort*)alloc(2 * 128 * 128 * sizeof(ushort));
    ushort* Ws2    = (ushort*)alloc(2 * 128 * 128 * sizeof(ushort));

    const int gridP = 512;
    const int epb = (E + gridP - 1) / gridP;
    const int gemmGrid = (N + 127) / 128;

    // K0: W pre-split + cursor init
    wsplit_init<<<128, 256, 0, stream>>>(W1, W2, Ws1, Ws2, cur, nb);
    // K1: gemm1 (x@W1 -> h bf16) fused with bucket_place (independent work)
    gemm1_place<<<gemmGrid + gridP, 256, 0, stream>>>(x, Ws1, h, N, gemmGrid,
                                                      esrc, edst, cur, ppack,
                                                      E, nb, epb);
    // K2: finalize -> csrsrc + meta + dinv
    csr_finalize<<<nb, 256, 0, stream>>>(ppack, cur, csrsrc, meta, dinv, N);
    // K3: layer-1 aggregate -> d_out (bf16 scratch)
    agg_kernel<true, true><<<(N + 7) / 8, 256, 0, stream>>>(h, dinv, meta, csrsrc,
                                                            b1, d_out, N);
    // K4: gemm2 (d_out@W2 -> h bf16)
    gemm_mfma<1><<<gemmGrid, 256, 0, stream>>>(d_out, Ws2, h, N);
    // K5: layer-2 aggregate -> d_out (fp32 final)
    agg_kernel<false, false><<<(N + 7) / 8, 256, 0, stream>>>(h, dinv, meta, csrsrc,
                                                              b2, d_out, N);
}